// Round 6
// baseline (322.404 us; speedup 1.0000x reference)
//
#include <hip/hip_runtime.h>

typedef unsigned short u16;
typedef __attribute__((ext_vector_type(8))) short short8;
typedef __attribute__((ext_vector_type(4))) float floatx4;

#define N_TOK 2048
#define DIM   2048
#define NH    32
#define NKVH  4
#define HD    64
#define KVD   256

__device__ __forceinline__ float bf2f(u16 u) {
  union { unsigned i; float f; } c; c.i = ((unsigned)u) << 16; return c.f;
}
__device__ __forceinline__ u16 f2bf(float f) {
  union { float f; unsigned i; } c; c.f = f;
  unsigned x = c.i;
  return (u16)((x + 0x7fffu + ((x >> 16) & 1u)) >> 16);
}

// async global->LDS, 16B per lane (dest = wave-uniform base + lane*16)
__device__ __forceinline__ void gload16(const u16* g, u16* l) {
#if defined(__has_builtin) && __has_builtin(__builtin_amdgcn_global_load_lds)
  __builtin_amdgcn_global_load_lds(
      (const __attribute__((address_space(1))) void*)g,
      (__attribute__((address_space(3))) void*)l, 16, 0, 0);
#else
  *(short8*)l = *(const short8*)g;
#endif
}

// ---------------------------------------------------------------------------
// Fused fp32 -> bf16 conversion of all 7 inputs (sizes in float4 units).
// ---------------------------------------------------------------------------
#define C_X  1048576
#define C_WQ 2097152
#define C_WK 2228224
#define C_WV 2359296
#define C_WO 3407872
#define C_CS 3440640
#define C_SN 3473408
__global__ __launch_bounds__(256) void cvt_all(const float* __restrict__ x,
                                               const float* __restrict__ wq,
                                               const float* __restrict__ wk,
                                               const float* __restrict__ wv,
                                               const float* __restrict__ wo,
                                               const float* __restrict__ cs,
                                               const float* __restrict__ sn,
                                               u16* __restrict__ dst) {
  int i = blockIdx.x * 256 + threadIdx.x;
  const float* src; int off;
  if      (i < C_X)  { src = x;  off = 0; }
  else if (i < C_WQ) { src = wq; off = C_X; }
  else if (i < C_WK) { src = wk; off = C_WQ; }
  else if (i < C_WV) { src = wv; off = C_WK; }
  else if (i < C_WO) { src = wo; off = C_WV; }
  else if (i < C_CS) { src = cs; off = C_WO; }
  else               { src = sn; off = C_CS; }
  float4 v = ((const float4*)src)[i - off];
  ushort4 o;
  o.x = f2bf(v.x); o.y = f2bf(v.y); o.z = f2bf(v.z); o.w = f2bf(v.w);
  ((ushort4*)dst)[i] = o;
}

// ---------------------------------------------------------------------------
// Fused QKV projection GEMM, m97 structure. 128x128 tiles, BK=32.
// tn 0..15 -> Q; 16..17 -> K; 18..19 -> V (written transposed Vt[256][N_TOK]).
// ---------------------------------------------------------------------------
__global__ __launch_bounds__(256) void gemm_qkv(const u16* __restrict__ A,
                                                const u16* __restrict__ Wq,
                                                const u16* __restrict__ Wk,
                                                const u16* __restrict__ Wv,
                                                u16* __restrict__ Qb,
                                                u16* __restrict__ Kb,
                                                u16* __restrict__ Vt) {
  __shared__ __align__(16) u16 As[128 * 32];
  __shared__ __align__(16) u16 Bs[128 * 32];
  const int tid  = threadIdx.x;
  const int lane = tid & 63;
  const int w    = tid >> 6;
  const int r    = lane & 15, q = lane >> 4;
  const int tm = blockIdx.x & 15;
  const int tn = blockIdx.x >> 4;   // 0..19
  const int wm = w & 1, wn = w >> 1;
  const int K = DIM;

  const u16* W; int wrow0;
  if (tn < 16)      { W = Wq; wrow0 = tn * 128; }
  else if (tn < 18) { W = Wk; wrow0 = (tn - 16) * 128; }
  else              { W = Wv; wrow0 = (tn - 18) * 128; }

  const int srow = w * 16 + (lane >> 2);
  const int scol = (lane & 3) * 8;
  const u16* ga = A + (size_t)(tm * 128 + srow) * K + scol;
  const u16* gb = W + (size_t)(wrow0 + srow) * K + scol;
  u16* lA = &As[w * 512 + lane * 8];
  u16* lB = &Bs[w * 512 + lane * 8];

  floatx4 acc[4][4];
#pragma unroll
  for (int a = 0; a < 4; ++a)
#pragma unroll
    for (int b = 0; b < 4; ++b) acc[a][b] = (floatx4){0.f, 0.f, 0.f, 0.f};

  for (int k0 = 0; k0 < K; k0 += 32) {
    __syncthreads();
    gload16(ga + k0, lA);
    gload16(ga + k0 + (size_t)64 * K, lA + 2048);
    gload16(gb + k0, lB);
    gload16(gb + k0 + (size_t)64 * K, lB + 2048);
    __syncthreads();

    short8 af[4], bf[4];
#pragma unroll
    for (int mi = 0; mi < 4; ++mi)
      af[mi] = *(const short8*)&As[(wm * 64 + mi * 16 + r) * 32 + q * 8];
#pragma unroll
    for (int nj = 0; nj < 4; ++nj)
      bf[nj] = *(const short8*)&Bs[(wn * 64 + nj * 16 + r) * 32 + q * 8];
#pragma unroll
    for (int mi = 0; mi < 4; ++mi)
#pragma unroll
      for (int nj = 0; nj < 4; ++nj)
        acc[mi][nj] = __builtin_amdgcn_mfma_f32_16x16x32_bf16(af[mi], bf[nj], acc[mi][nj], 0, 0, 0);
  }

  if (tn < 16) {            // Q: [token][2048]
#pragma unroll
    for (int mi = 0; mi < 4; ++mi)
#pragma unroll
      for (int g = 0; g < 4; ++g) {
        int row = tm * 128 + wm * 64 + mi * 16 + 4 * q + g;
#pragma unroll
        for (int nj = 0; nj < 4; ++nj)
          Qb[(size_t)row * DIM + tn * 128 + wn * 64 + nj * 16 + r] = f2bf(acc[mi][nj][g]);
      }
  } else if (tn < 18) {     // K: [token][256]
#pragma unroll
    for (int mi = 0; mi < 4; ++mi)
#pragma unroll
      for (int g = 0; g < 4; ++g) {
        int row = tm * 128 + wm * 64 + mi * 16 + 4 * q + g;
#pragma unroll
        for (int nj = 0; nj < 4; ++nj)
          Kb[(size_t)row * KVD + (tn - 16) * 128 + wn * 64 + nj * 16 + r] = f2bf(acc[mi][nj][g]);
      }
  } else {                  // V transposed: Vt[col][token], packed 8B stores
#pragma unroll
    for (int mi = 0; mi < 4; ++mi)
#pragma unroll
      for (int nj = 0; nj < 4; ++nj) {
        int col  = (tn - 18) * 128 + wn * 64 + nj * 16 + r;
        int row0 = tm * 128 + wm * 64 + mi * 16 + 4 * q;
        uint2 pk;
        pk.x = (unsigned)f2bf(acc[mi][nj][0]) | ((unsigned)f2bf(acc[mi][nj][1]) << 16);
        pk.y = (unsigned)f2bf(acc[mi][nj][2]) | ((unsigned)f2bf(acc[mi][nj][3]) << 16);
        *(uint2*)(Vt + (size_t)col * N_TOK + row0) = pk;
      }
  }
}

// ---------------------------------------------------------------------------
// Output GEMM (m97 structure), fp32 out.
// ---------------------------------------------------------------------------
__global__ __launch_bounds__(256) void gemm128(const u16* __restrict__ A,
                                               const u16* __restrict__ W,
                                               float* __restrict__ C,
                                               int M, int Nout, int K) {
  __shared__ __align__(16) u16 As[128 * 32];
  __shared__ __align__(16) u16 Bs[128 * 32];
  const int tid  = threadIdx.x;
  const int lane = tid & 63;
  const int w    = tid >> 6;
  const int r    = lane & 15, q = lane >> 4;
  const int tiles_n = Nout >> 7;
  const int tm = blockIdx.x / tiles_n;
  const int tn = blockIdx.x % tiles_n;
  const int wm = w & 1, wn = w >> 1;

  const int srow = w * 16 + (lane >> 2);
  const int scol = (lane & 3) * 8;
  const u16* ga = A + (size_t)(tm * 128 + srow) * K + scol;
  const u16* gb = W + (size_t)(tn * 128 + srow) * K + scol;
  u16* lA = &As[w * 512 + lane * 8];
  u16* lB = &Bs[w * 512 + lane * 8];

  floatx4 acc[4][4];
#pragma unroll
  for (int a = 0; a < 4; ++a)
#pragma unroll
    for (int b = 0; b < 4; ++b) acc[a][b] = (floatx4){0.f, 0.f, 0.f, 0.f};

  for (int k0 = 0; k0 < K; k0 += 32) {
    __syncthreads();
    gload16(ga + k0, lA);
    gload16(ga + k0 + (size_t)64 * K, lA + 2048);
    gload16(gb + k0, lB);
    gload16(gb + k0 + (size_t)64 * K, lB + 2048);
    __syncthreads();

    short8 af[4], bf[4];
#pragma unroll
    for (int mi = 0; mi < 4; ++mi)
      af[mi] = *(const short8*)&As[(wm * 64 + mi * 16 + r) * 32 + q * 8];
#pragma unroll
    for (int nj = 0; nj < 4; ++nj)
      bf[nj] = *(const short8*)&Bs[(wn * 64 + nj * 16 + r) * 32 + q * 8];
#pragma unroll
    for (int mi = 0; mi < 4; ++mi)
#pragma unroll
      for (int nj = 0; nj < 4; ++nj)
        acc[mi][nj] = __builtin_amdgcn_mfma_f32_16x16x32_bf16(af[mi], bf[nj], acc[mi][nj], 0, 0, 0);
  }

#pragma unroll
  for (int mi = 0; mi < 4; ++mi)
#pragma unroll
    for (int g = 0; g < 4; ++g) {
      int row = tm * 128 + wm * 64 + mi * 16 + 4 * q + g;
#pragma unroll
      for (int nj = 0; nj < 4; ++nj)
        C[(size_t)row * Nout + tn * 128 + wn * 64 + nj * 16 + r] = acc[mi][nj][g];
    }
}

// ---------------------------------------------------------------------------
// RoPE in-place on Q and K in one launch. First NQ pair-indices -> Q (nh=32),
// rest -> K (nh=4).
// ---------------------------------------------------------------------------
#define NQ_PAIRS (N_TOK * NH * 32)
#define NK_PAIRS (N_TOK * NKVH * 32)
__global__ __launch_bounds__(256) void rope_all(u16* __restrict__ Qb,
                                                u16* __restrict__ Kb,
                                                const u16* __restrict__ cosb,
                                                const u16* __restrict__ sinb) {
  int idx = blockIdx.x * 256 + threadIdx.x;
  u16* T; int nh;
  if (idx < NQ_PAIRS) { T = Qb; nh = NH; }
  else                { T = Kb; nh = NKVH; idx -= NQ_PAIRS; }
  int d  = idx & 31;
  int t  = idx >> 5;
  int hh = t % nh;
  int n  = t / nh;
  size_t base = (size_t)n * nh * 64 + (size_t)hh * 64;
  float x1 = bf2f(T[base + d]);
  float x2 = bf2f(T[base + d + 32]);
  float c1 = bf2f(cosb[n * 64 + d]);
  float s1 = bf2f(sinb[n * 64 + d]);
  float c2 = bf2f(cosb[n * 64 + d + 32]);
  float s2 = bf2f(sinb[n * 64 + d + 32]);
  T[base + d]      = f2bf(x1 * c1 - x2 * s1);
  T[base + d + 32] = f2bf(x2 * c2 + x1 * s2);
}

// ---------------------------------------------------------------------------
// Split-K barrier-free MFMA flash attention computing S^T (A=K, B=Q).
// Grid (16 qt, 32 h, 2 split). Block = 4 independent waves; wave w owns
// q-rows qt*128 + w*32 .. +31. Split z covers key tiles [0,qt] or
// [qt+1, 2qt+1] (balanced). Outputs UNNORMALIZED O partial (bf16) + l partial
// (fp32); combine kernel adds and normalizes (valid since no max-tracking).
// S^T C-layout: lane(q,r) value g = (key 16t+4q+g, qrow r) -> packed b64 P
// writes, scalar per-lane l accumulation.
// ---------------------------------------------------------------------------
__global__ __launch_bounds__(256) void attn_mfma(const u16* __restrict__ Qb,
                                                 const u16* __restrict__ Kb,
                                                 const u16* __restrict__ Vt,
                                                 u16* __restrict__ Op,
                                                 float* __restrict__ lp) {
  __shared__ __align__(16) u16 Pl[4][32][72];
  const int tid  = threadIdx.x;
  const int lane = tid & 63;
  const int w    = tid >> 6;
  const int r    = lane & 15;
  const int q    = lane >> 4;
  const int bx   = blockIdx.x;
  const int qt   = (bx & 1) ? (15 - (bx >> 1)) : (bx >> 1);
  const int h    = blockIdx.y;
  const int z    = blockIdx.z;
  const int kvh  = h >> 3;
  const int baseq = qt * 128 + w * 32;
  const u16* Vh = Vt + (size_t)(kvh * 64) * N_TOK;

  const int kt0 = z ? (qt + 1) : 0;
  const int kt1 = z ? (2 * qt + 1) : qt;   // inclusive

  // Q B-frags: qf[i][c] lane(q,r) -> Q[baseq+16i+r][h*64 + 32c + 8q + j]
  short8 qf[2][2];
#pragma unroll
  for (int i = 0; i < 2; ++i) {
    const u16* qp = Qb + (size_t)(baseq + 16 * i + r) * DIM + h * 64 + q * 8;
    qf[i][0] = *(const short8*)(qp);
    qf[i][1] = *(const short8*)(qp + 32);
  }

  floatx4 O[2][4];
  float lsum[2];
#pragma unroll
  for (int i = 0; i < 2; ++i) {
    lsum[i] = 0.f;
#pragma unroll
    for (int t = 0; t < 4; ++t) O[i][t] = (floatx4){0.f, 0.f, 0.f, 0.f};
  }

  for (int kt = kt0; kt <= kt1; ++kt) {
    // ---- S^T = K Q^T ----
    floatx4 ST[2][4];   // [i][keyblock t]
#pragma unroll
    for (int i = 0; i < 2; ++i)
#pragma unroll
      for (int t = 0; t < 4; ++t) ST[i][t] = (floatx4){0.f, 0.f, 0.f, 0.f};
#pragma unroll
    for (int t = 0; t < 4; ++t) {
      const u16* kp = Kb + (size_t)(kt * 64 + 16 * t + r) * KVD + kvh * 64 + q * 8;
      short8 kf0 = *(const short8*)(kp);
      short8 kf1 = *(const short8*)(kp + 32);
#pragma unroll
      for (int i = 0; i < 2; ++i) {
        ST[i][t] = __builtin_amdgcn_mfma_f32_16x16x32_bf16(kf0, qf[i][0], ST[i][t], 0, 0, 0);
        ST[i][t] = __builtin_amdgcn_mfma_f32_16x16x32_bf16(kf1, qf[i][1], ST[i][t], 0, 0, 0);
      }
    }

    // ---- causal mask: key = kt*64+16t+4q+g, qrow = baseq+16i+r ----
    if (kt >= 2 * qt) {
#pragma unroll
      for (int i = 0; i < 2; ++i) {
        int qrow = baseq + 16 * i + r;
#pragma unroll
        for (int t = 0; t < 4; ++t) {
          int key = kt * 64 + 16 * t + 4 * q;
#pragma unroll
          for (int g = 0; g < 4; ++g)
            if (key + g > qrow) ST[i][t][g] = -1e30f;
        }
      }
    }

    // ---- p = exp(scale*s); per-lane scalar row-sum; packed P -> LDS ----
#pragma unroll
    for (int i = 0; i < 2; ++i)
#pragma unroll
      for (int t = 0; t < 4; ++t) {
        float p0 = __expf(0.125f * ST[i][t][0]);
        float p1 = __expf(0.125f * ST[i][t][1]);
        float p2 = __expf(0.125f * ST[i][t][2]);
        float p3 = __expf(0.125f * ST[i][t][3]);
        lsum[i] += (p0 + p1) + (p2 + p3);
        uint2 pk;
        pk.x = (unsigned)f2bf(p0) | ((unsigned)f2bf(p1) << 16);
        pk.y = (unsigned)f2bf(p2) | ((unsigned)f2bf(p3) << 16);
        *(uint2*)&Pl[w][16 * i + r][16 * t + 4 * q] = pk;   // ds_write_b64
      }

    // ---- O += P V  (A = P rows from LDS, B = Vt rows from global/L2) ----
#pragma unroll
    for (int s = 0; s < 2; ++s) {
      short8 vb[4];
#pragma unroll
      for (int t = 0; t < 4; ++t)
        vb[t] = *(const short8*)(Vh + (size_t)(16 * t + r) * N_TOK + kt * 64 + 32 * s + 8 * q);
#pragma unroll
      for (int i = 0; i < 2; ++i) {
        short8 pa = *(const short8*)&Pl[w][16 * i + r][32 * s + 8 * q];
#pragma unroll
        for (int t = 0; t < 4; ++t)
          O[i][t] = __builtin_amdgcn_mfma_f32_16x16x32_bf16(pa, vb[t], O[i][t], 0, 0, 0);
      }
    }
  }

  // ---- epilogue: reduce l over q-groups (lanes sharing r), store partials --
#pragma unroll
  for (int i = 0; i < 2; ++i) {
    lsum[i] += __shfl_xor(lsum[i], 16);
    lsum[i] += __shfl_xor(lsum[i], 32);
  }
  if (q == 0) {
#pragma unroll
    for (int i = 0; i < 2; ++i)
      lp[(size_t)z * NH * N_TOK + (size_t)h * N_TOK + baseq + 16 * i + r] = lsum[i];
  }

  u16* Oz = Op + (size_t)z * N_TOK * DIM;
#pragma unroll
  for (int i = 0; i < 2; ++i)
#pragma unroll
    for (int g = 0; g < 4; ++g) {
      u16* yp = Oz + (size_t)(baseq + 16 * i + 4 * q + g) * DIM + h * 64 + r;
      yp[0]  = f2bf(O[i][0][g]);
      yp[16] = f2bf(O[i][1][g]);
      yp[32] = f2bf(O[i][2][g]);
      yp[48] = f2bf(O[i][3][g]);
    }
}

// ---------------------------------------------------------------------------
// Combine: Yb = (O0 + O1) / (l0 + l1). 8 elems/thread.
// ---------------------------------------------------------------------------
__global__ __launch_bounds__(256) void combine(const u16* __restrict__ Op,
                                               const float* __restrict__ lp,
                                               u16* __restrict__ Yb) {
  int idx = blockIdx.x * 256 + threadIdx.x;     // per 8-elem chunk
  int tok = idx >> 8;
  int rem = idx & 255;
  int h   = rem >> 3;
  float l = lp[(size_t)h * N_TOK + tok] + lp[(size_t)NH * N_TOK + (size_t)h * N_TOK + tok];
  float inv = 1.f / l;
  const short8 a = *(const short8*)(Op + (size_t)idx * 8);
  const short8 b = *(const short8*)(Op + (size_t)N_TOK * DIM + (size_t)idx * 8);
  ushort4 o0, o1;
  o0.x = f2bf((bf2f((u16)a[0]) + bf2f((u16)b[0])) * inv);
  o0.y = f2bf((bf2f((u16)a[1]) + bf2f((u16)b[1])) * inv);
  o0.z = f2bf((bf2f((u16)a[2]) + bf2f((u16)b[2])) * inv);
  o0.w = f2bf((bf2f((u16)a[3]) + bf2f((u16)b[3])) * inv);
  o1.x = f2bf((bf2f((u16)a[4]) + bf2f((u16)b[4])) * inv);
  o1.y = f2bf((bf2f((u16)a[5]) + bf2f((u16)b[5])) * inv);
  o1.z = f2bf((bf2f((u16)a[6]) + bf2f((u16)b[6])) * inv);
  o1.w = f2bf((bf2f((u16)a[7]) + bf2f((u16)b[7])) * inv);
  ((ushort4*)Yb)[idx * 2]     = o0;
  ((ushort4*)Yb)[idx * 2 + 1] = o1;
}

// ---------------------------------------------------------------------------
extern "C" void kernel_launch(void* const* d_in, const int* in_sizes, int n_in,
                              void* d_out, int out_size, void* d_ws, size_t ws_size,
                              hipStream_t stream) {
  const float* x  = (const float*)d_in[0];
  const float* Wq = (const float*)d_in[1];
  const float* Wk = (const float*)d_in[2];
  const float* Wv = (const float*)d_in[3];
  const float* Wo = (const float*)d_in[4];
  const float* cs = (const float*)d_in[5];
  const float* sn = (const float*)d_in[6];

  u16* ws  = (u16*)d_ws;
  u16* xb  = ws;                            // order must match cvt_all segments
  u16* Wqb = xb  + (size_t)N_TOK * DIM;
  u16* Wkb = Wqb + (size_t)DIM * DIM;
  u16* Wvb = Wkb + (size_t)KVD * DIM;
  u16* Wob = Wvb + (size_t)KVD * DIM;
  u16* csb = Wob + (size_t)DIM * DIM;
  u16* snb = csb + (size_t)N_TOK * HD;
  u16* Qb  = snb + (size_t)N_TOK * HD;
  u16* Kb  = Qb  + (size_t)N_TOK * DIM;
  u16* Vtb = Kb  + (size_t)N_TOK * KVD;     // transposed V [256][N_TOK]
  u16* Yb  = Vtb + (size_t)N_TOK * KVD;

  // Aliases for attention partials over buffers dead after gemm_qkv:
  u16*   Op = xb;               // [2][N_TOK][DIM] bf16 = xb (4M) + Wqb (4M)
  float* lp = (float*)Wkb;      // [2][NH][N_TOK] fp32 = 512 KB (fits in Wkb)

  cvt_all<<<dim3(13568), 256, 0, stream>>>(x, Wq, Wk, Wv, Wo, cs, sn, ws);

  // Fused QKV projection (V written transposed)
  gemm_qkv<<<dim3(320), 256, 0, stream>>>(xb, Wqb, Wkb, Wvb, Qb, Kb, Vtb);

  // RoPE on Q and K, single launch
  rope_all<<<dim3((NQ_PAIRS + NK_PAIRS) / 256), 256, 0, stream>>>(Qb, Kb, csb, snb);

  // Split-K attention: 16 q-tiles x 32 heads x 2 key-splits
  attn_mfma<<<dim3(16, 32, 2), 256, 0, stream>>>(Qb, Kb, Vtb, Op, lp);

  // Combine partials -> Yb
  combine<<<dim3(N_TOK * DIM / 8 / 256), 256, 0, stream>>>(Op, lp, Yb);

  // Output projection (fp32 straight to d_out)
  gemm128<<<dim3(256), 256, 0, stream>>>(Yb, Wob, (float*)d_out, N_TOK, DIM, DIM);
}

// Round 7
// 293.749 us; speedup vs baseline: 1.0975x; 1.0975x over previous
//
#include <hip/hip_runtime.h>

typedef unsigned short u16;
typedef __attribute__((ext_vector_type(8))) short short8;
typedef __attribute__((ext_vector_type(4))) float floatx4;

#define N_TOK 2048
#define DIM   2048
#define NH    32
#define NKVH  4
#define HD    64
#define KVD   256

__device__ __forceinline__ float bf2f(u16 u) {
  union { unsigned i; float f; } c; c.i = ((unsigned)u) << 16; return c.f;
}
__device__ __forceinline__ u16 f2bf(float f) {
  union { float f; unsigned i; } c; c.f = f;
  unsigned x = c.i;
  return (u16)((x + 0x7fffu + ((x >> 16) & 1u)) >> 16);
}

// async global->LDS, 16B per lane (dest = wave-uniform base + lane*16)
__device__ __forceinline__ void gload16(const u16* g, u16* l) {
#if defined(__has_builtin) && __has_builtin(__builtin_amdgcn_global_load_lds)
  __builtin_amdgcn_global_load_lds(
      (const __attribute__((address_space(1))) void*)g,
      (__attribute__((address_space(3))) void*)l, 16, 0, 0);
#else
  *(short8*)l = *(const short8*)g;
#endif
}

// ---------------------------------------------------------------------------
// Fused fp32 -> bf16 conversion of x, Wq, Wk, Wv, Wo (float4 units).
// cos/sin stay fp32 (consumed directly by the fused-rope GEMM epilogue).
// ---------------------------------------------------------------------------
#define C_X  1048576
#define C_WQ 2097152
#define C_WK 2228224
#define C_WV 2359296
#define C_WO 3407872
__global__ __launch_bounds__(256) void cvt_all(const float* __restrict__ x,
                                               const float* __restrict__ wq,
                                               const float* __restrict__ wk,
                                               const float* __restrict__ wv,
                                               const float* __restrict__ wo,
                                               u16* __restrict__ dst) {
  int i = blockIdx.x * 256 + threadIdx.x;
  const float* src; int off;
  if      (i < C_X)  { src = x;  off = 0; }
  else if (i < C_WQ) { src = wq; off = C_X; }
  else if (i < C_WK) { src = wk; off = C_WQ; }
  else if (i < C_WV) { src = wv; off = C_WK; }
  else               { src = wo; off = C_WV; }
  float4 v = ((const float4*)src)[i - off];
  ushort4 o;
  o.x = f2bf(v.x); o.y = f2bf(v.y); o.z = f2bf(v.z); o.w = f2bf(v.w);
  ((ushort4*)dst)[i] = o;
}

// ---------------------------------------------------------------------------
// Fused QKV projection GEMM, 64x128 tiles, BK=32, RoPE fused in epilogue.
// Grid 640: tm = bid&31 (32 m-tiles), tn = bid>>5 (0..19):
//   tn 0..15 -> Q (+rope); 16..17 -> K (+rope); 18..19 -> V transposed.
// Block = 4 waves in 2x2: wave (wm,wn) covers m 32*wm.., n 64*wn..
// ---------------------------------------------------------------------------
__global__ __launch_bounds__(256) void gemm_qkv(const u16* __restrict__ A,
                                                const u16* __restrict__ Wq,
                                                const u16* __restrict__ Wk,
                                                const u16* __restrict__ Wv,
                                                const float* __restrict__ cs,
                                                const float* __restrict__ sn,
                                                u16* __restrict__ Qb,
                                                u16* __restrict__ Kb,
                                                u16* __restrict__ Vt) {
  __shared__ __align__(16) u16 As[64 * 32];
  __shared__ __align__(16) u16 Bs[128 * 32];
  const int tid  = threadIdx.x;
  const int lane = tid & 63;
  const int w    = tid >> 6;
  const int r    = lane & 15, q = lane >> 4;
  const int tm = blockIdx.x & 31;
  const int tn = blockIdx.x >> 5;   // 0..19
  const int wm = w & 1, wn = w >> 1;
  const int K = DIM;

  const u16* W; int wrow0;
  if (tn < 16)      { W = Wq; wrow0 = tn * 128; }
  else if (tn < 18) { W = Wk; wrow0 = (tn - 16) * 128; }
  else              { W = Wv; wrow0 = (tn - 18) * 128; }

  const int srow = tid >> 2;          // 0..63
  const int scol = (tid & 3) * 8;
  const u16* ga = A + (size_t)(tm * 64 + srow) * K + scol;
  const u16* gb = W + (size_t)(wrow0 + srow) * K + scol;
  u16* lA = &As[tid * 8];
  u16* lB = &Bs[tid * 8];

  floatx4 acc[2][4];
#pragma unroll
  for (int a = 0; a < 2; ++a)
#pragma unroll
    for (int b = 0; b < 4; ++b) acc[a][b] = (floatx4){0.f, 0.f, 0.f, 0.f};

  for (int k0 = 0; k0 < K; k0 += 32) {
    __syncthreads();
    gload16(ga + k0, lA);
    gload16(gb + k0, lB);
    gload16(gb + k0 + (size_t)64 * K, lB + 2048);
    __syncthreads();

    short8 af[2], bf[4];
#pragma unroll
    for (int mi = 0; mi < 2; ++mi)
      af[mi] = *(const short8*)&As[(wm * 32 + mi * 16 + r) * 32 + q * 8];
#pragma unroll
    for (int nj = 0; nj < 4; ++nj)
      bf[nj] = *(const short8*)&Bs[(wn * 64 + nj * 16 + r) * 32 + q * 8];
#pragma unroll
    for (int mi = 0; mi < 2; ++mi)
#pragma unroll
      for (int nj = 0; nj < 4; ++nj)
        acc[mi][nj] = __builtin_amdgcn_mfma_f32_16x16x32_bf16(af[mi], bf[nj], acc[mi][nj], 0, 0, 0);
  }

  if (tn < 18) {
    // Q or K with fused RoPE. Head dim = 64 aligns with the wn*64 block:
    // d = nj*16 + r (nj<2 pairs with nj+2 = d+32).
    u16* Out;
    int  ostride, colbase;
    if (tn < 16) { Out = Qb; ostride = DIM; colbase = tn * 128 + wn * 64; }
    else         { Out = Kb; ostride = KVD; colbase = (tn - 16) * 128 + wn * 64; }
#pragma unroll
    for (int mi = 0; mi < 2; ++mi)
#pragma unroll
      for (int g = 0; g < 4; ++g) {
        int row = tm * 64 + wm * 32 + mi * 16 + 4 * q + g;
        const float* crow = cs + (size_t)row * 64;
        const float* srow2 = sn + (size_t)row * 64;
        u16* orow = Out + (size_t)row * ostride + colbase;
#pragma unroll
        for (int nj = 0; nj < 2; ++nj) {
          int d = nj * 16 + r;
          float x0 = acc[mi][nj][g];       // value at dim d
          float x1 = acc[mi][nj + 2][g];   // value at dim d+32
          float o0 = x0 * crow[d]      - x1 * srow2[d];
          float o1 = x1 * crow[d + 32] + x0 * srow2[d + 32];
          orow[d]      = f2bf(o0);
          orow[d + 32] = f2bf(o1);
        }
      }
  } else {
    // V transposed: Vt[col][token], packed 8B stores (4 consecutive tokens)
#pragma unroll
    for (int mi = 0; mi < 2; ++mi)
#pragma unroll
      for (int nj = 0; nj < 4; ++nj) {
        int col  = (tn - 18) * 128 + wn * 64 + nj * 16 + r;
        int row0 = tm * 64 + wm * 32 + mi * 16 + 4 * q;
        uint2 pk;
        pk.x = (unsigned)f2bf(acc[mi][nj][0]) | ((unsigned)f2bf(acc[mi][nj][1]) << 16);
        pk.y = (unsigned)f2bf(acc[mi][nj][2]) | ((unsigned)f2bf(acc[mi][nj][3]) << 16);
        *(uint2*)(Vt + (size_t)col * N_TOK + row0) = pk;
      }
  }
}

// ---------------------------------------------------------------------------
// Output GEMM, 64x128 tiles, BK=32, fp32 out. Grid 512: tn=bid&15, tm=bid>>4.
// ---------------------------------------------------------------------------
__global__ __launch_bounds__(256) void gemm_out(const u16* __restrict__ A,
                                                const u16* __restrict__ W,
                                                float* __restrict__ C) {
  __shared__ __align__(16) u16 As[64 * 32];
  __shared__ __align__(16) u16 Bs[128 * 32];
  const int tid  = threadIdx.x;
  const int lane = tid & 63;
  const int w    = tid >> 6;
  const int r    = lane & 15, q = lane >> 4;
  const int tn = blockIdx.x & 15;
  const int tm = blockIdx.x >> 4;
  const int wm = w & 1, wn = w >> 1;
  const int K = DIM;

  const int srow = tid >> 2;
  const int scol = (tid & 3) * 8;
  const u16* ga = A + (size_t)(tm * 64 + srow) * K + scol;
  const u16* gb = W + (size_t)(tn * 128 + srow) * K + scol;
  u16* lA = &As[tid * 8];
  u16* lB = &Bs[tid * 8];

  floatx4 acc[2][4];
#pragma unroll
  for (int a = 0; a < 2; ++a)
#pragma unroll
    for (int b = 0; b < 4; ++b) acc[a][b] = (floatx4){0.f, 0.f, 0.f, 0.f};

  for (int k0 = 0; k0 < K; k0 += 32) {
    __syncthreads();
    gload16(ga + k0, lA);
    gload16(gb + k0, lB);
    gload16(gb + k0 + (size_t)64 * K, lB + 2048);
    __syncthreads();

    short8 af[2], bf[4];
#pragma unroll
    for (int mi = 0; mi < 2; ++mi)
      af[mi] = *(const short8*)&As[(wm * 32 + mi * 16 + r) * 32 + q * 8];
#pragma unroll
    for (int nj = 0; nj < 4; ++nj)
      bf[nj] = *(const short8*)&Bs[(wn * 64 + nj * 16 + r) * 32 + q * 8];
#pragma unroll
    for (int mi = 0; mi < 2; ++mi)
#pragma unroll
      for (int nj = 0; nj < 4; ++nj)
        acc[mi][nj] = __builtin_amdgcn_mfma_f32_16x16x32_bf16(af[mi], bf[nj], acc[mi][nj], 0, 0, 0);
  }

#pragma unroll
  for (int mi = 0; mi < 2; ++mi)
#pragma unroll
    for (int g = 0; g < 4; ++g) {
      int row = tm * 64 + wm * 32 + mi * 16 + 4 * q + g;
#pragma unroll
      for (int nj = 0; nj < 4; ++nj)
        C[(size_t)row * DIM + tn * 128 + wn * 64 + nj * 16 + r] = acc[mi][nj][g];
    }
}

// ---------------------------------------------------------------------------
// Single-wave barrier-free MFMA flash attention (S^T form: A=K, B=Q).
// Grid (64, 32): bx -> (qt 0..15 swizzled, sub 0..3); wave owns q-rows
// baseq = qt*128 + sub*32 .. +31. Keys 0..baseq+31 (ktmax = (baseq+31)>>6).
// No __syncthreads, 4.6 KB LDS -> many independent resident waves per CU.
// No max-tracking (|s|*scale << 80); row-sum normalized in-register via shfl.
// ---------------------------------------------------------------------------
__global__ __launch_bounds__(64) void attn_mfma(const u16* __restrict__ Qb,
                                                const u16* __restrict__ Kb,
                                                const u16* __restrict__ Vt,
                                                u16* __restrict__ Yb) {
  __shared__ __align__(16) u16 Pl[32][72];
  const int lane = threadIdx.x;
  const int r    = lane & 15;
  const int q    = lane >> 4;
  const int bx   = blockIdx.x;
  const int q6   = bx >> 2;
  const int qt   = (q6 & 1) ? (15 - (q6 >> 1)) : (q6 >> 1);  // load balance
  const int sub  = bx & 3;
  const int h    = blockIdx.y;
  const int kvh  = h >> 3;
  const int baseq = qt * 128 + sub * 32;
  const u16* Vh = Vt + (size_t)(kvh * 64) * N_TOK;

  // Q B-frags: qf[i][c] lane(q,r) -> Q[baseq+16i+r][h*64 + 32c + 8q + j]
  short8 qf[2][2];
#pragma unroll
  for (int i = 0; i < 2; ++i) {
    const u16* qp = Qb + (size_t)(baseq + 16 * i + r) * DIM + h * 64 + q * 8;
    qf[i][0] = *(const short8*)(qp);
    qf[i][1] = *(const short8*)(qp + 32);
  }

  floatx4 O[2][4];
  float lsum[2];
#pragma unroll
  for (int i = 0; i < 2; ++i) {
    lsum[i] = 0.f;
#pragma unroll
    for (int t = 0; t < 4; ++t) O[i][t] = (floatx4){0.f, 0.f, 0.f, 0.f};
  }

  const int ktmax = (baseq + 31) >> 6;   // inclusive
  for (int kt = 0; kt <= ktmax; ++kt) {
    // ---- S^T = K Q^T ----
    floatx4 ST[2][4];
#pragma unroll
    for (int i = 0; i < 2; ++i)
#pragma unroll
      for (int t = 0; t < 4; ++t) ST[i][t] = (floatx4){0.f, 0.f, 0.f, 0.f};
#pragma unroll
    for (int t = 0; t < 4; ++t) {
      const u16* kp = Kb + (size_t)(kt * 64 + 16 * t + r) * KVD + kvh * 64 + q * 8;
      short8 kf0 = *(const short8*)(kp);
      short8 kf1 = *(const short8*)(kp + 32);
#pragma unroll
      for (int i = 0; i < 2; ++i) {
        ST[i][t] = __builtin_amdgcn_mfma_f32_16x16x32_bf16(kf0, qf[i][0], ST[i][t], 0, 0, 0);
        ST[i][t] = __builtin_amdgcn_mfma_f32_16x16x32_bf16(kf1, qf[i][1], ST[i][t], 0, 0, 0);
      }
    }

    // ---- causal mask (only the last tile can clip) ----
    if (kt == ktmax) {
#pragma unroll
      for (int i = 0; i < 2; ++i) {
        int qrow = baseq + 16 * i + r;
#pragma unroll
        for (int t = 0; t < 4; ++t) {
          int key = kt * 64 + 16 * t + 4 * q;
#pragma unroll
          for (int g = 0; g < 4; ++g)
            if (key + g > qrow) ST[i][t][g] = -1e30f;
        }
      }
    }

    // ---- p = exp(scale*s); per-lane partial row-sums; packed P -> LDS ----
#pragma unroll
    for (int i = 0; i < 2; ++i)
#pragma unroll
      for (int t = 0; t < 4; ++t) {
        float p0 = __expf(0.125f * ST[i][t][0]);
        float p1 = __expf(0.125f * ST[i][t][1]);
        float p2 = __expf(0.125f * ST[i][t][2]);
        float p3 = __expf(0.125f * ST[i][t][3]);
        lsum[i] += (p0 + p1) + (p2 + p3);
        uint2 pk;
        pk.x = (unsigned)f2bf(p0) | ((unsigned)f2bf(p1) << 16);
        pk.y = (unsigned)f2bf(p2) | ((unsigned)f2bf(p3) << 16);
        *(uint2*)&Pl[16 * i + r][16 * t + 4 * q] = pk;   // ds_write_b64
      }

    // ---- O += P V  (A = P rows from LDS, B = Vt rows from global/L2) ----
#pragma unroll
    for (int s = 0; s < 2; ++s) {
      short8 vb[4];
#pragma unroll
      for (int t = 0; t < 4; ++t)
        vb[t] = *(const short8*)(Vh + (size_t)(16 * t + r) * N_TOK + kt * 64 + 32 * s + 8 * q);
#pragma unroll
      for (int i = 0; i < 2; ++i) {
        short8 pa = *(const short8*)&Pl[16 * i + r][32 * s + 8 * q];
#pragma unroll
        for (int t = 0; t < 4; ++t)
          O[i][t] = __builtin_amdgcn_mfma_f32_16x16x32_bf16(pa, vb[t], O[i][t], 0, 0, 0);
      }
    }
  }

  // ---- reduce row-sums over q-groups (lanes sharing r), fetch per-row inv --
#pragma unroll
  for (int i = 0; i < 2; ++i) {
    lsum[i] += __shfl_xor(lsum[i], 16);
    lsum[i] += __shfl_xor(lsum[i], 32);   // now lane(q,r) holds sum for row r
  }

#pragma unroll
  for (int i = 0; i < 2; ++i) {
    float inv[4];
#pragma unroll
    for (int g = 0; g < 4; ++g)
      inv[g] = 1.f / __shfl(lsum[i], 4 * q + g);   // row 4q+g sum lives in lane r=4q+g
#pragma unroll
    for (int g = 0; g < 4; ++g) {
      u16* yp = Yb + (size_t)(baseq + 16 * i + 4 * q + g) * DIM + h * 64 + r;
      yp[0]  = f2bf(O[i][0][g] * inv[g]);
      yp[16] = f2bf(O[i][1][g] * inv[g]);
      yp[32] = f2bf(O[i][2][g] * inv[g]);
      yp[48] = f2bf(O[i][3][g] * inv[g]);
    }
  }
}

// ---------------------------------------------------------------------------
extern "C" void kernel_launch(void* const* d_in, const int* in_sizes, int n_in,
                              void* d_out, int out_size, void* d_ws, size_t ws_size,
                              hipStream_t stream) {
  const float* x  = (const float*)d_in[0];
  const float* Wq = (const float*)d_in[1];
  const float* Wk = (const float*)d_in[2];
  const float* Wv = (const float*)d_in[3];
  const float* Wo = (const float*)d_in[4];
  const float* cs = (const float*)d_in[5];
  const float* sn = (const float*)d_in[6];

  u16* ws  = (u16*)d_ws;
  u16* xb  = ws;                            // order must match cvt_all segments
  u16* Wqb = xb  + (size_t)N_TOK * DIM;
  u16* Wkb = Wqb + (size_t)DIM * DIM;
  u16* Wvb = Wkb + (size_t)KVD * DIM;
  u16* Wob = Wvb + (size_t)KVD * DIM;
  u16* Qb  = Wob + (size_t)DIM * DIM;
  u16* Kb  = Qb  + (size_t)N_TOK * DIM;
  u16* Vtb = Kb  + (size_t)N_TOK * KVD;     // transposed V [256][N_TOK]
  u16* Yb  = Vtb + (size_t)N_TOK * KVD;

  // fp32 -> bf16 (x + 4 weights); cos/sin consumed as fp32 by gemm_qkv
  cvt_all<<<dim3(13312), 256, 0, stream>>>(x, Wq, Wk, Wv, Wo, ws);

  // Fused QKV projection + RoPE epilogue (V written transposed)
  gemm_qkv<<<dim3(640), 256, 0, stream>>>(xb, Wqb, Wkb, Wvb, cs, sn, Qb, Kb, Vtb);

  // Single-wave barrier-free attention: (16 qt x 4 sub) x 32 heads
  attn_mfma<<<dim3(64, 32), 64, 0, stream>>>(Qb, Kb, Vtb, Yb);

  // Output projection (fp32 straight to d_out)
  gemm_out<<<dim3(512), 256, 0, stream>>>(Yb, Wob, (float*)d_out);
}

// Round 8
// 291.664 us; speedup vs baseline: 1.1054x; 1.0071x over previous
//
#include <hip/hip_runtime.h>

typedef unsigned short u16;
typedef __attribute__((ext_vector_type(8))) short short8;
typedef __attribute__((ext_vector_type(4))) float floatx4;

#define N_TOK 2048
#define DIM   2048
#define NH    32
#define NKVH  4
#define HD    64
#define KVD   256

__device__ __forceinline__ float bf2f(u16 u) {
  union { unsigned i; float f; } c; c.i = ((unsigned)u) << 16; return c.f;
}
__device__ __forceinline__ u16 f2bf(float f) {
  union { float f; unsigned i; } c; c.f = f;
  unsigned x = c.i;
  return (u16)((x + 0x7fffu + ((x >> 16) & 1u)) >> 16);
}

// async global->LDS, 16B per lane (dest = wave-uniform base + lane*16)
__device__ __forceinline__ void gload16(const u16* g, u16* l) {
#if defined(__has_builtin) && __has_builtin(__builtin_amdgcn_global_load_lds)
  __builtin_amdgcn_global_load_lds(
      (const __attribute__((address_space(1))) void*)g,
      (__attribute__((address_space(3))) void*)l, 16, 0, 0);
#else
  *(short8*)l = *(const short8*)g;
#endif
}

// ---------------------------------------------------------------------------
// Fused fp32 -> bf16 conversion of x, Wq, Wk, Wv, Wo (float4 units).
// ---------------------------------------------------------------------------
#define C_X  1048576
#define C_WQ 2097152
#define C_WK 2228224
#define C_WV 2359296
#define C_WO 3407872
__global__ __launch_bounds__(256) void cvt_all(const float* __restrict__ x,
                                               const float* __restrict__ wq,
                                               const float* __restrict__ wk,
                                               const float* __restrict__ wv,
                                               const float* __restrict__ wo,
                                               u16* __restrict__ dst) {
  int i = blockIdx.x * 256 + threadIdx.x;
  const float* src; int off;
  if      (i < C_X)  { src = x;  off = 0; }
  else if (i < C_WQ) { src = wq; off = C_X; }
  else if (i < C_WK) { src = wk; off = C_WQ; }
  else if (i < C_WV) { src = wv; off = C_WK; }
  else               { src = wo; off = C_WV; }
  float4 v = ((const float4*)src)[i - off];
  ushort4 o;
  o.x = f2bf(v.x); o.y = f2bf(v.y); o.z = f2bf(v.z); o.w = f2bf(v.w);
  ((ushort4*)dst)[i] = o;
}

// ---------------------------------------------------------------------------
// Fused QKV projection GEMM, 64x128 tiles, BK=32, RoPE fused in epilogue.
// Grid 640: tm = bid&31, tn = bid>>5 (0..19):
//   tn 0..15 -> Q (+rope); 16..17 -> K (+rope); 18..19 -> V transposed.
// ---------------------------------------------------------------------------
__global__ __launch_bounds__(256) void gemm_qkv(const u16* __restrict__ A,
                                                const u16* __restrict__ Wq,
                                                const u16* __restrict__ Wk,
                                                const u16* __restrict__ Wv,
                                                const float* __restrict__ cs,
                                                const float* __restrict__ sn,
                                                u16* __restrict__ Qb,
                                                u16* __restrict__ Kb,
                                                u16* __restrict__ Vt) {
  __shared__ __align__(16) u16 As[64 * 32];
  __shared__ __align__(16) u16 Bs[128 * 32];
  const int tid  = threadIdx.x;
  const int lane = tid & 63;
  const int w    = tid >> 6;
  const int r    = lane & 15, q = lane >> 4;
  const int tm = blockIdx.x & 31;
  const int tn = blockIdx.x >> 5;   // 0..19
  const int wm = w & 1, wn = w >> 1;
  const int K = DIM;

  const u16* W; int wrow0;
  if (tn < 16)      { W = Wq; wrow0 = tn * 128; }
  else if (tn < 18) { W = Wk; wrow0 = (tn - 16) * 128; }
  else              { W = Wv; wrow0 = (tn - 18) * 128; }

  const int srow = tid >> 2;          // 0..63
  const int scol = (tid & 3) * 8;
  const u16* ga = A + (size_t)(tm * 64 + srow) * K + scol;
  const u16* gb = W + (size_t)(wrow0 + srow) * K + scol;
  u16* lA = &As[tid * 8];
  u16* lB = &Bs[tid * 8];

  floatx4 acc[2][4];
#pragma unroll
  for (int a = 0; a < 2; ++a)
#pragma unroll
    for (int b = 0; b < 4; ++b) acc[a][b] = (floatx4){0.f, 0.f, 0.f, 0.f};

  for (int k0 = 0; k0 < K; k0 += 32) {
    __syncthreads();
    gload16(ga + k0, lA);
    gload16(gb + k0, lB);
    gload16(gb + k0 + (size_t)64 * K, lB + 2048);
    __syncthreads();

    short8 af[2], bf[4];
#pragma unroll
    for (int mi = 0; mi < 2; ++mi)
      af[mi] = *(const short8*)&As[(wm * 32 + mi * 16 + r) * 32 + q * 8];
#pragma unroll
    for (int nj = 0; nj < 4; ++nj)
      bf[nj] = *(const short8*)&Bs[(wn * 64 + nj * 16 + r) * 32 + q * 8];
#pragma unroll
    for (int mi = 0; mi < 2; ++mi)
#pragma unroll
      for (int nj = 0; nj < 4; ++nj)
        acc[mi][nj] = __builtin_amdgcn_mfma_f32_16x16x32_bf16(af[mi], bf[nj], acc[mi][nj], 0, 0, 0);
  }

  if (tn < 18) {
    u16* Out;
    int  ostride, colbase;
    if (tn < 16) { Out = Qb; ostride = DIM; colbase = tn * 128 + wn * 64; }
    else         { Out = Kb; ostride = KVD; colbase = (tn - 16) * 128 + wn * 64; }
#pragma unroll
    for (int mi = 0; mi < 2; ++mi)
#pragma unroll
      for (int g = 0; g < 4; ++g) {
        int row = tm * 64 + wm * 32 + mi * 16 + 4 * q + g;
        const float* crow = cs + (size_t)row * 64;
        const float* srow2 = sn + (size_t)row * 64;
        u16* orow = Out + (size_t)row * ostride + colbase;
#pragma unroll
        for (int nj = 0; nj < 2; ++nj) {
          int d = nj * 16 + r;
          float x0 = acc[mi][nj][g];       // value at dim d
          float x1 = acc[mi][nj + 2][g];   // value at dim d+32
          float o0 = x0 * crow[d]      - x1 * srow2[d];
          float o1 = x1 * crow[d + 32] + x0 * srow2[d + 32];
          orow[d]      = f2bf(o0);
          orow[d + 32] = f2bf(o1);
        }
      }
  } else {
#pragma unroll
    for (int mi = 0; mi < 2; ++mi)
#pragma unroll
      for (int nj = 0; nj < 4; ++nj) {
        int col  = (tn - 18) * 128 + wn * 64 + nj * 16 + r;
        int row0 = tm * 64 + wm * 32 + mi * 16 + 4 * q;
        uint2 pk;
        pk.x = (unsigned)f2bf(acc[mi][nj][0]) | ((unsigned)f2bf(acc[mi][nj][1]) << 16);
        pk.y = (unsigned)f2bf(acc[mi][nj][2]) | ((unsigned)f2bf(acc[mi][nj][3]) << 16);
        *(uint2*)(Vt + (size_t)col * N_TOK + row0) = pk;
      }
  }
}

// ---------------------------------------------------------------------------
// Output GEMM, 64x128 tiles, BK=32, fp32 out. Grid 512: tn=bid&15, tm=bid>>4.
// ---------------------------------------------------------------------------
__global__ __launch_bounds__(256) void gemm_out(const u16* __restrict__ A,
                                                const u16* __restrict__ W,
                                                float* __restrict__ C) {
  __shared__ __align__(16) u16 As[64 * 32];
  __shared__ __align__(16) u16 Bs[128 * 32];
  const int tid  = threadIdx.x;
  const int lane = tid & 63;
  const int w    = tid >> 6;
  const int r    = lane & 15, q = lane >> 4;
  const int tn = blockIdx.x & 15;
  const int tm = blockIdx.x >> 4;
  const int wm = w & 1, wn = w >> 1;
  const int K = DIM;

  const int srow = tid >> 2;
  const int scol = (tid & 3) * 8;
  const u16* ga = A + (size_t)(tm * 64 + srow) * K + scol;
  const u16* gb = W + (size_t)(tn * 128 + srow) * K + scol;
  u16* lA = &As[tid * 8];
  u16* lB = &Bs[tid * 8];

  floatx4 acc[2][4];
#pragma unroll
  for (int a = 0; a < 2; ++a)
#pragma unroll
    for (int b = 0; b < 4; ++b) acc[a][b] = (floatx4){0.f, 0.f, 0.f, 0.f};

  for (int k0 = 0; k0 < K; k0 += 32) {
    __syncthreads();
    gload16(ga + k0, lA);
    gload16(gb + k0, lB);
    gload16(gb + k0 + (size_t)64 * K, lB + 2048);
    __syncthreads();

    short8 af[2], bf[4];
#pragma unroll
    for (int mi = 0; mi < 2; ++mi)
      af[mi] = *(const short8*)&As[(wm * 32 + mi * 16 + r) * 32 + q * 8];
#pragma unroll
    for (int nj = 0; nj < 4; ++nj)
      bf[nj] = *(const short8*)&Bs[(wn * 64 + nj * 16 + r) * 32 + q * 8];
#pragma unroll
    for (int mi = 0; mi < 2; ++mi)
#pragma unroll
      for (int nj = 0; nj < 4; ++nj)
        acc[mi][nj] = __builtin_amdgcn_mfma_f32_16x16x32_bf16(af[mi], bf[nj], acc[mi][nj], 0, 0, 0);
  }

#pragma unroll
  for (int mi = 0; mi < 2; ++mi)
#pragma unroll
    for (int g = 0; g < 4; ++g) {
      int row = tm * 64 + wm * 32 + mi * 16 + 4 * q + g;
#pragma unroll
      for (int nj = 0; nj < 4; ++nj)
        C[(size_t)row * DIM + tn * 128 + wn * 64 + nj * 16 + r] = acc[mi][nj][g];
    }
}

// ---------------------------------------------------------------------------
// Single-wave barrier-free MFMA flash attention (S^T form), K-register
// software pipeline: K(kt+1) prefetched into a second register buffer at the
// top of iteration kt (consumed one full iteration later); V(kt) issued at
// body start, consumed after QK->exp->LDS (~500 cyc of independent work).
// Manual 2x unroll swaps the K buffers by reference -> no register copies.
// Grid (64, 32): heaviest (largest baseq) blocks first.
// ---------------------------------------------------------------------------
__global__ __launch_bounds__(64) void attn_mfma(const u16* __restrict__ Qb,
                                                const u16* __restrict__ Kb,
                                                const u16* __restrict__ Vt,
                                                u16* __restrict__ Yb) {
  __shared__ __align__(16) u16 Pl[32][72];
  const int lane = threadIdx.x;
  const int r    = lane & 15;
  const int q    = lane >> 4;
  const int bx   = blockIdx.x;
  const int qt   = 15 - (bx >> 2);
  const int sub  = 3 - (bx & 3);
  const int h    = blockIdx.y;
  const int kvh  = h >> 3;
  const int baseq = qt * 128 + sub * 32;
  const u16* Vh = Vt + (size_t)(kvh * 64) * N_TOK;
  const int ktmax = (baseq + 31) >> 6;   // inclusive

  // Q B-frags
  short8 qf[2][2];
#pragma unroll
  for (int i = 0; i < 2; ++i) {
    const u16* qp = Qb + (size_t)(baseq + 16 * i + r) * DIM + h * 64 + q * 8;
    qf[i][0] = *(const short8*)(qp);
    qf[i][1] = *(const short8*)(qp + 32);
  }

  floatx4 O[2][4];
  float lsum[2];
#pragma unroll
  for (int i = 0; i < 2; ++i) {
    lsum[i] = 0.f;
#pragma unroll
    for (int t = 0; t < 4; ++t) O[i][t] = (floatx4){0.f, 0.f, 0.f, 0.f};
  }

  auto loadK = [&](int kt, short8 (&kf)[4][2]) {
#pragma unroll
    for (int t = 0; t < 4; ++t) {
      const u16* kp = Kb + (size_t)(kt * 64 + 16 * t + r) * KVD + kvh * 64 + q * 8;
      kf[t][0] = *(const short8*)(kp);
      kf[t][1] = *(const short8*)(kp + 32);
    }
  };

  auto body = [&](int kt, short8 (&kc)[4][2], short8 (&kn)[4][2]) {
    // V for CURRENT tile: issued first, consumed at the bottom
    short8 vb[2][4];
#pragma unroll
    for (int s = 0; s < 2; ++s)
#pragma unroll
      for (int t = 0; t < 4; ++t)
        vb[s][t] = *(const short8*)(Vh + (size_t)(16 * t + r) * N_TOK + kt * 64 + 32 * s + 8 * q);

    // K for NEXT tile: issued now, consumed next body (clamped, branchless)
    loadK(kt < ktmax ? kt + 1 : ktmax, kn);

    // ---- S^T = K Q^T (kc already resident) ----
    floatx4 ST[2][4];
#pragma unroll
    for (int i = 0; i < 2; ++i)
#pragma unroll
      for (int t = 0; t < 4; ++t) ST[i][t] = (floatx4){0.f, 0.f, 0.f, 0.f};
#pragma unroll
    for (int t = 0; t < 4; ++t)
#pragma unroll
      for (int i = 0; i < 2; ++i) {
        ST[i][t] = __builtin_amdgcn_mfma_f32_16x16x32_bf16(kc[t][0], qf[i][0], ST[i][t], 0, 0, 0);
        ST[i][t] = __builtin_amdgcn_mfma_f32_16x16x32_bf16(kc[t][1], qf[i][1], ST[i][t], 0, 0, 0);
      }

    // ---- causal mask (only the last tile can clip) ----
    if (kt == ktmax) {
#pragma unroll
      for (int i = 0; i < 2; ++i) {
        int qrow = baseq + 16 * i + r;
#pragma unroll
        for (int t = 0; t < 4; ++t) {
          int key = kt * 64 + 16 * t + 4 * q;
#pragma unroll
          for (int g = 0; g < 4; ++g)
            if (key + g > qrow) ST[i][t][g] = -1e30f;
        }
      }
    }

    // ---- p = exp(scale*s); per-lane partial row-sums; packed P -> LDS ----
#pragma unroll
    for (int i = 0; i < 2; ++i)
#pragma unroll
      for (int t = 0; t < 4; ++t) {
        float p0 = __expf(0.125f * ST[i][t][0]);
        float p1 = __expf(0.125f * ST[i][t][1]);
        float p2 = __expf(0.125f * ST[i][t][2]);
        float p3 = __expf(0.125f * ST[i][t][3]);
        lsum[i] += (p0 + p1) + (p2 + p3);
        uint2 pk;
        pk.x = (unsigned)f2bf(p0) | ((unsigned)f2bf(p1) << 16);
        pk.y = (unsigned)f2bf(p2) | ((unsigned)f2bf(p3) << 16);
        *(uint2*)&Pl[16 * i + r][16 * t + 4 * q] = pk;   // ds_write_b64
      }

    // ---- O += P V ----
#pragma unroll
    for (int s = 0; s < 2; ++s)
#pragma unroll
      for (int i = 0; i < 2; ++i) {
        short8 pa = *(const short8*)&Pl[16 * i + r][32 * s + 8 * q];
#pragma unroll
        for (int t = 0; t < 4; ++t)
          O[i][t] = __builtin_amdgcn_mfma_f32_16x16x32_bf16(pa, vb[s][t], O[i][t], 0, 0, 0);
      }
  };

  short8 kA[4][2], kB[4][2];
  loadK(0, kA);
  for (int kt = 0; kt <= ktmax; kt += 2) {
    body(kt, kA, kB);
    if (kt + 1 <= ktmax) body(kt + 1, kB, kA);
  }

  // ---- reduce row-sums over q-groups, normalize, store ----
#pragma unroll
  for (int i = 0; i < 2; ++i) {
    lsum[i] += __shfl_xor(lsum[i], 16);
    lsum[i] += __shfl_xor(lsum[i], 32);   // lane(q,r) holds sum for row r
  }

#pragma unroll
  for (int i = 0; i < 2; ++i) {
    float inv[4];
#pragma unroll
    for (int g = 0; g < 4; ++g)
      inv[g] = 1.f / __shfl(lsum[i], 4 * q + g);
#pragma unroll
    for (int g = 0; g < 4; ++g) {
      u16* yp = Yb + (size_t)(baseq + 16 * i + 4 * q + g) * DIM + h * 64 + r;
      yp[0]  = f2bf(O[i][0][g] * inv[g]);
      yp[16] = f2bf(O[i][1][g] * inv[g]);
      yp[32] = f2bf(O[i][2][g] * inv[g]);
      yp[48] = f2bf(O[i][3][g] * inv[g]);
    }
  }
}

// ---------------------------------------------------------------------------
extern "C" void kernel_launch(void* const* d_in, const int* in_sizes, int n_in,
                              void* d_out, int out_size, void* d_ws, size_t ws_size,
                              hipStream_t stream) {
  const float* x  = (const float*)d_in[0];
  const float* Wq = (const float*)d_in[1];
  const float* Wk = (const float*)d_in[2];
  const float* Wv = (const float*)d_in[3];
  const float* Wo = (const float*)d_in[4];
  const float* cs = (const float*)d_in[5];
  const float* sn = (const float*)d_in[6];

  u16* ws  = (u16*)d_ws;
  u16* xb  = ws;                            // order must match cvt_all segments
  u16* Wqb = xb  + (size_t)N_TOK * DIM;
  u16* Wkb = Wqb + (size_t)DIM * DIM;
  u16* Wvb = Wkb + (size_t)KVD * DIM;
  u16* Wob = Wvb + (size_t)KVD * DIM;
  u16* Qb  = Wob + (size_t)DIM * DIM;
  u16* Kb  = Qb  + (size_t)N_TOK * DIM;
  u16* Vtb = Kb  + (size_t)N_TOK * KVD;     // transposed V [256][N_TOK]
  u16* Yb  = Vtb + (size_t)N_TOK * KVD;

  // fp32 -> bf16 (x + 4 weights); cos/sin consumed as fp32 by gemm_qkv
  cvt_all<<<dim3(13312), 256, 0, stream>>>(x, Wq, Wk, Wv, Wo, ws);

  // Fused QKV projection + RoPE epilogue (V written transposed)
  gemm_qkv<<<dim3(640), 256, 0, stream>>>(xb, Wqb, Wkb, Wvb, cs, sn, Qb, Kb, Vtb);

  // Single-wave pipelined attention: (16 qt x 4 sub) x 32 heads
  attn_mfma<<<dim3(64, 32), 64, 0, stream>>>(Qb, Kb, Vtb, Yb);

  // Output projection (fp32 straight to d_out)
  gemm_out<<<dim3(512), 256, 0, stream>>>(Yb, Wob, (float*)d_out);
}

// Round 9
// 226.307 us; speedup vs baseline: 1.4246x; 1.2888x over previous
//
#include <hip/hip_runtime.h>

typedef unsigned short u16;
typedef __attribute__((ext_vector_type(8))) short short8;
typedef __attribute__((ext_vector_type(4))) float floatx4;

#define N_TOK 2048
#define DIM   2048
#define NH    32
#define NKVH  4
#define HD    64
#define KVD   256

__device__ __forceinline__ float bf2f(u16 u) {
  union { unsigned i; float f; } c; c.i = ((unsigned)u) << 16; return c.f;
}
__device__ __forceinline__ u16 f2bf(float f) {
  union { float f; unsigned i; } c; c.f = f;
  unsigned x = c.i;
  return (u16)((x + 0x7fffu + ((x >> 16) & 1u)) >> 16);
}

// async global->LDS, 16B per lane (dest = wave-uniform base + lane*16)
__device__ __forceinline__ void gload16(const u16* g, u16* l) {
#if defined(__has_builtin) && __has_builtin(__builtin_amdgcn_global_load_lds)
  __builtin_amdgcn_global_load_lds(
      (const __attribute__((address_space(1))) void*)g,
      (__attribute__((address_space(3))) void*)l, 16, 0, 0);
#else
  *(short8*)l = *(const short8*)g;
#endif
}

// ---------------------------------------------------------------------------
// Fused fp32 -> bf16 conversion of x, Wq, Wk, Wv, Wo (float4 units).
// ---------------------------------------------------------------------------
#define C_X  1048576
#define C_WQ 2097152
#define C_WK 2228224
#define C_WV 2359296
#define C_WO 3407872
__global__ __launch_bounds__(256) void cvt_all(const float* __restrict__ x,
                                               const float* __restrict__ wq,
                                               const float* __restrict__ wk,
                                               const float* __restrict__ wv,
                                               const float* __restrict__ wo,
                                               u16* __restrict__ dst) {
  int i = blockIdx.x * 256 + threadIdx.x;
  const float* src; int off;
  if      (i < C_X)  { src = x;  off = 0; }
  else if (i < C_WQ) { src = wq; off = C_X; }
  else if (i < C_WK) { src = wk; off = C_WQ; }
  else if (i < C_WV) { src = wv; off = C_WK; }
  else               { src = wo; off = C_WV; }
  float4 v = ((const float4*)src)[i - off];
  ushort4 o;
  o.x = f2bf(v.x); o.y = f2bf(v.y); o.z = f2bf(v.z); o.w = f2bf(v.w);
  ((ushort4*)dst)[i] = o;
}

// ===========================================================================
// FRAG-PACKED LAYOUTS (u16 indices; lane = q*16 + r, q=lane>>4, r=lane&15):
//  Qp: [(h*64 + sq)*4 + i*2 + c]*512 + lane*8 + j
//      = Q_rope[token = sq*32 + 16i + r][dim = h*64 + 32c + 8q + j]
//  Kp: [((kvh*32 + kt)*8) + t*2 + c]*512 + lane*8 + j
//      = K_rope[token = kt*64 + 16t + r][dim = kvh*64 + 32c + 8q + j]
//  Vp: [((kvh*32 + kt)*8) + s*4 + t]*512 + lane*8 + j
//      = V[token = kt*64 + 32s + 8q + j][dim = kvh*64 + 16t + r]
// Every attention fragment load = one contiguous 1KB wave read.
// ===========================================================================

// ---------------------------------------------------------------------------
// Fused QKV projection GEMM, 64x128 tiles, BK=32, RoPE fused, frag-packed out.
// Grid 640: tm = bid&31, tn = bid>>5 (0..19): 0..15 Q; 16..17 K; 18..19 V.
// ---------------------------------------------------------------------------
__global__ __launch_bounds__(256) void gemm_qkv(const u16* __restrict__ A,
                                                const u16* __restrict__ Wq,
                                                const u16* __restrict__ Wk,
                                                const u16* __restrict__ Wv,
                                                const float* __restrict__ cs,
                                                const float* __restrict__ sn,
                                                u16* __restrict__ Qp,
                                                u16* __restrict__ Kp,
                                                u16* __restrict__ Vp) {
  __shared__ __align__(16) u16 As[64 * 32];
  __shared__ __align__(16) u16 Bs[128 * 32];
  const int tid  = threadIdx.x;
  const int lane = tid & 63;
  const int w    = tid >> 6;
  const int r    = lane & 15, q = lane >> 4;
  const int tm = blockIdx.x & 31;
  const int tn = blockIdx.x >> 5;   // 0..19
  const int wm = w & 1, wn = w >> 1;
  const int K = DIM;

  const u16* W; int wrow0;
  if (tn < 16)      { W = Wq; wrow0 = tn * 128; }
  else if (tn < 18) { W = Wk; wrow0 = (tn - 16) * 128; }
  else              { W = Wv; wrow0 = (tn - 18) * 128; }

  const int srow = tid >> 2;          // 0..63
  const int scol = (tid & 3) * 8;
  const u16* ga = A + (size_t)(tm * 64 + srow) * K + scol;
  const u16* gb = W + (size_t)(wrow0 + srow) * K + scol;
  u16* lA = &As[tid * 8];
  u16* lB = &Bs[tid * 8];

  floatx4 acc[2][4];
#pragma unroll
  for (int a = 0; a < 2; ++a)
#pragma unroll
    for (int b = 0; b < 4; ++b) acc[a][b] = (floatx4){0.f, 0.f, 0.f, 0.f};

  for (int k0 = 0; k0 < K; k0 += 32) {
    __syncthreads();
    gload16(ga + k0, lA);
    gload16(gb + k0, lB);
    gload16(gb + k0 + (size_t)64 * K, lB + 2048);
    __syncthreads();

    short8 af[2], bf[4];
#pragma unroll
    for (int mi = 0; mi < 2; ++mi)
      af[mi] = *(const short8*)&As[(wm * 32 + mi * 16 + r) * 32 + q * 8];
#pragma unroll
    for (int nj = 0; nj < 4; ++nj)
      bf[nj] = *(const short8*)&Bs[(wn * 64 + nj * 16 + r) * 32 + q * 8];
#pragma unroll
    for (int mi = 0; mi < 2; ++mi)
#pragma unroll
      for (int nj = 0; nj < 4; ++nj)
        acc[mi][nj] = __builtin_amdgcn_mfma_f32_16x16x32_bf16(af[mi], bf[nj], acc[mi][nj], 0, 0, 0);
  }

  if (tn < 18) {
    // Q or K with fused RoPE, written frag-packed.
    const int head = (tn < 16) ? (tn * 2 + wn) : ((tn - 16) * 2 + wn);
#pragma unroll
    for (int mi = 0; mi < 2; ++mi)
#pragma unroll
      for (int g = 0; g < 4; ++g) {
        int row = tm * 64 + wm * 32 + mi * 16 + 4 * q + g;   // token
        const float* crow  = cs + (size_t)row * 64;
        const float* srow2 = sn + (size_t)row * 64;
#pragma unroll
        for (int nj = 0; nj < 2; ++nj) {
          int d = nj * 16 + r;               // head-dim 0..31 (pairs with d+32)
          float x0 = acc[mi][nj][g];
          float x1 = acc[mi][nj + 2][g];
          float o0 = x0 * crow[d]      - x1 * srow2[d];
          float o1 = x1 * crow[d + 32] + x0 * srow2[d + 32];
          int qq = d >> 3, j = d & 7;        // frag coords for both c=0 and c=1
          int lslot = (qq * 16 + (row & 15)) * 8 + j;
          if (tn < 16) {
            int sq = row >> 5, ii = (row >> 4) & 1;
            size_t base = ((size_t)(head * 64 + sq) * 4 + ii * 2) * 512 + lslot;
            Qp[base]       = f2bf(o0);       // c=0
            Qp[base + 512] = f2bf(o1);       // c=1
          } else {
            int kt = row >> 6, t = (row >> 4) & 3;
            size_t base = ((size_t)(head * 32 + kt) * 8 + t * 2) * 512 + lslot;
            Kp[base]       = f2bf(o0);
            Kp[base + 512] = f2bf(o1);
          }
        }
      }
  } else {
    // V frag-packed: uint2 = 4 consecutive tokens (j0 = (4q)&7 in {0,4})
#pragma unroll
    for (int mi = 0; mi < 2; ++mi)
#pragma unroll
      for (int nj = 0; nj < 4; ++nj) {
        int col  = (tn - 18) * 128 + wn * 64 + nj * 16 + r;   // dim 0..255
        int kvh  = col >> 6;
        int t    = (col & 63) >> 4;        // = nj
        int rr   = col & 15;               // = r
        int row0 = tm * 64 + wm * 32 + mi * 16 + 4 * q;       // token
        int kt   = row0 >> 6;
        int wk   = row0 & 63;
        int s    = wk >> 5;
        int qq   = (wk & 31) >> 3;
        int j0   = wk & 7;                 // 0 or 4
        uint2 pk;
        pk.x = (unsigned)f2bf(acc[mi][nj][0]) | ((unsigned)f2bf(acc[mi][nj][1]) << 16);
        pk.y = (unsigned)f2bf(acc[mi][nj][2]) | ((unsigned)f2bf(acc[mi][nj][3]) << 16);
        size_t idx = ((size_t)(kvh * 32 + kt) * 8 + s * 4 + t) * 512 + (qq * 16 + rr) * 8 + j0;
        *(uint2*)(Vp + idx) = pk;
      }
  }
}

// ---------------------------------------------------------------------------
// Output GEMM, 64x128 tiles, BK=32, fp32 out. Grid 512: tn=bid&15, tm=bid>>4.
// ---------------------------------------------------------------------------
__global__ __launch_bounds__(256) void gemm_out(const u16* __restrict__ A,
                                                const u16* __restrict__ W,
                                                float* __restrict__ C) {
  __shared__ __align__(16) u16 As[64 * 32];
  __shared__ __align__(16) u16 Bs[128 * 32];
  const int tid  = threadIdx.x;
  const int lane = tid & 63;
  const int w    = tid >> 6;
  const int r    = lane & 15, q = lane >> 4;
  const int tn = blockIdx.x & 15;
  const int tm = blockIdx.x >> 4;
  const int wm = w & 1, wn = w >> 1;
  const int K = DIM;

  const int srow = tid >> 2;
  const int scol = (tid & 3) * 8;
  const u16* ga = A + (size_t)(tm * 64 + srow) * K + scol;
  const u16* gb = W + (size_t)(tn * 128 + srow) * K + scol;
  u16* lA = &As[tid * 8];
  u16* lB = &Bs[tid * 8];

  floatx4 acc[2][4];
#pragma unroll
  for (int a = 0; a < 2; ++a)
#pragma unroll
    for (int b = 0; b < 4; ++b) acc[a][b] = (floatx4){0.f, 0.f, 0.f, 0.f};

  for (int k0 = 0; k0 < K; k0 += 32) {
    __syncthreads();
    gload16(ga + k0, lA);
    gload16(gb + k0, lB);
    gload16(gb + k0 + (size_t)64 * K, lB + 2048);
    __syncthreads();

    short8 af[2], bf[4];
#pragma unroll
    for (int mi = 0; mi < 2; ++mi)
      af[mi] = *(const short8*)&As[(wm * 32 + mi * 16 + r) * 32 + q * 8];
#pragma unroll
    for (int nj = 0; nj < 4; ++nj)
      bf[nj] = *(const short8*)&Bs[(wn * 64 + nj * 16 + r) * 32 + q * 8];
#pragma unroll
    for (int mi = 0; mi < 2; ++mi)
#pragma unroll
      for (int nj = 0; nj < 4; ++nj)
        acc[mi][nj] = __builtin_amdgcn_mfma_f32_16x16x32_bf16(af[mi], bf[nj], acc[mi][nj], 0, 0, 0);
  }

#pragma unroll
  for (int mi = 0; mi < 2; ++mi)
#pragma unroll
    for (int g = 0; g < 4; ++g) {
      int row = tm * 64 + wm * 32 + mi * 16 + 4 * q + g;
#pragma unroll
      for (int nj = 0; nj < 4; ++nj)
        C[(size_t)row * DIM + tn * 128 + wn * 64 + nj * 16 + r] = acc[mi][nj][g];
    }
}

// ---------------------------------------------------------------------------
// Single-wave barrier-free MFMA flash attention, frag-packed inputs:
// every K/V/Q fragment load is one contiguous 1KB wave read (base + lane*16).
// K register double-buffer prefetch; launch_bounds(64,2) -> ~256 VGPR budget
// so the prefetch stays hoisted (grid caps residency at 2 waves/SIMD anyway).
// ---------------------------------------------------------------------------
__global__ __launch_bounds__(64, 2) void attn_mfma(const u16* __restrict__ Qp,
                                                   const u16* __restrict__ Kp,
                                                   const u16* __restrict__ Vp,
                                                   u16* __restrict__ Yb) {
  __shared__ __align__(16) u16 Pl[32][72];
  const int lane = threadIdx.x;
  const int r    = lane & 15;
  const int q    = lane >> 4;
  const int bx   = blockIdx.x;
  const int qt   = 15 - (bx >> 2);
  const int sub  = 3 - (bx & 3);
  const int h    = blockIdx.y;
  const int kvh  = h >> 3;
  const int baseq = qt * 128 + sub * 32;
  const int sq   = baseq >> 5;
  const int ktmax = (baseq + 31) >> 6;   // inclusive

  // Q frags: one 1KB wave read each
  short8 qf[2][2];
#pragma unroll
  for (int i = 0; i < 2; ++i)
#pragma unroll
    for (int c = 0; c < 2; ++c)
      qf[i][c] = *(const short8*)(Qp + ((size_t)(h * 64 + sq) * 4 + i * 2 + c) * 512 + lane * 8);

  floatx4 O[2][4];
  float lsum[2];
#pragma unroll
  for (int i = 0; i < 2; ++i) {
    lsum[i] = 0.f;
#pragma unroll
    for (int t = 0; t < 4; ++t) O[i][t] = (floatx4){0.f, 0.f, 0.f, 0.f};
  }

  const u16* Kbase = Kp + (size_t)(kvh * 32) * 8 * 512;
  const u16* Vbase = Vp + (size_t)(kvh * 32) * 8 * 512;

  auto loadK = [&](int kt, short8 (&kf)[4][2]) {
    const u16* kb = Kbase + (size_t)kt * 8 * 512 + lane * 8;
#pragma unroll
    for (int t = 0; t < 4; ++t) {
      kf[t][0] = *(const short8*)(kb + (t * 2 + 0) * 512);
      kf[t][1] = *(const short8*)(kb + (t * 2 + 1) * 512);
    }
  };

  auto body = [&](int kt, short8 (&kc)[4][2], short8 (&kn)[4][2]) {
    // V for CURRENT tile: issued first, consumed at the bottom
    short8 vb[2][4];
    {
      const u16* vbp = Vbase + (size_t)kt * 8 * 512 + lane * 8;
#pragma unroll
      for (int s = 0; s < 2; ++s)
#pragma unroll
        for (int t = 0; t < 4; ++t)
          vb[s][t] = *(const short8*)(vbp + (s * 4 + t) * 512);
    }

    // K for NEXT tile: issued now, consumed next body (clamped, branchless)
    loadK(kt < ktmax ? kt + 1 : ktmax, kn);

    // ---- S^T = K Q^T (kc already resident) ----
    floatx4 ST[2][4];
#pragma unroll
    for (int i = 0; i < 2; ++i)
#pragma unroll
      for (int t = 0; t < 4; ++t) ST[i][t] = (floatx4){0.f, 0.f, 0.f, 0.f};
#pragma unroll
    for (int t = 0; t < 4; ++t)
#pragma unroll
      for (int i = 0; i < 2; ++i) {
        ST[i][t] = __builtin_amdgcn_mfma_f32_16x16x32_bf16(kc[t][0], qf[i][0], ST[i][t], 0, 0, 0);
        ST[i][t] = __builtin_amdgcn_mfma_f32_16x16x32_bf16(kc[t][1], qf[i][1], ST[i][t], 0, 0, 0);
      }

    // ---- causal mask (only the last tile can clip) ----
    if (kt == ktmax) {
#pragma unroll
      for (int i = 0; i < 2; ++i) {
        int qrow = baseq + 16 * i + r;
#pragma unroll
        for (int t = 0; t < 4; ++t) {
          int key = kt * 64 + 16 * t + 4 * q;
#pragma unroll
          for (int g = 0; g < 4; ++g)
            if (key + g > qrow) ST[i][t][g] = -1e30f;
        }
      }
    }

    // ---- p = exp(scale*s); per-lane partial row-sums; packed P -> LDS ----
#pragma unroll
    for (int i = 0; i < 2; ++i)
#pragma unroll
      for (int t = 0; t < 4; ++t) {
        float p0 = __expf(0.125f * ST[i][t][0]);
        float p1 = __expf(0.125f * ST[i][t][1]);
        float p2 = __expf(0.125f * ST[i][t][2]);
        float p3 = __expf(0.125f * ST[i][t][3]);
        lsum[i] += (p0 + p1) + (p2 + p3);
        uint2 pk;
        pk.x = (unsigned)f2bf(p0) | ((unsigned)f2bf(p1) << 16);
        pk.y = (unsigned)f2bf(p2) | ((unsigned)f2bf(p3) << 16);
        *(uint2*)&Pl[16 * i + r][16 * t + 4 * q] = pk;   // ds_write_b64
      }

    // ---- O += P V ----
#pragma unroll
    for (int s = 0; s < 2; ++s)
#pragma unroll
      for (int i = 0; i < 2; ++i) {
        short8 pa = *(const short8*)&Pl[16 * i + r][32 * s + 8 * q];
#pragma unroll
        for (int t = 0; t < 4; ++t)
          O[i][t] = __builtin_amdgcn_mfma_f32_16x16x32_bf16(pa, vb[s][t], O[i][t], 0, 0, 0);
      }
  };

  short8 kA[4][2], kB[4][2];
  loadK(0, kA);
  for (int kt = 0; kt <= ktmax; kt += 2) {
    body(kt, kA, kB);
    if (kt + 1 <= ktmax) body(kt + 1, kB, kA);
  }

  // ---- reduce row-sums over q-groups, normalize, store ----
#pragma unroll
  for (int i = 0; i < 2; ++i) {
    lsum[i] += __shfl_xor(lsum[i], 16);
    lsum[i] += __shfl_xor(lsum[i], 32);   // lane(q,r) holds sum for row r
  }

#pragma unroll
  for (int i = 0; i < 2; ++i) {
    float inv[4];
#pragma unroll
    for (int g = 0; g < 4; ++g)
      inv[g] = 1.f / __shfl(lsum[i], 4 * q + g);
#pragma unroll
    for (int g = 0; g < 4; ++g) {
      u16* yp = Yb + (size_t)(baseq + 16 * i + 4 * q + g) * DIM + h * 64 + r;
      yp[0]  = f2bf(O[i][0][g] * inv[g]);
      yp[16] = f2bf(O[i][1][g] * inv[g]);
      yp[32] = f2bf(O[i][2][g] * inv[g]);
      yp[48] = f2bf(O[i][3][g] * inv[g]);
    }
  }
}

// ---------------------------------------------------------------------------
extern "C" void kernel_launch(void* const* d_in, const int* in_sizes, int n_in,
                              void* d_out, int out_size, void* d_ws, size_t ws_size,
                              hipStream_t stream) {
  const float* x  = (const float*)d_in[0];
  const float* Wq = (const float*)d_in[1];
  const float* Wk = (const float*)d_in[2];
  const float* Wv = (const float*)d_in[3];
  const float* Wo = (const float*)d_in[4];
  const float* cs = (const float*)d_in[5];
  const float* sn = (const float*)d_in[6];

  u16* ws  = (u16*)d_ws;
  u16* xb  = ws;                            // order must match cvt_all segments
  u16* Wqb = xb  + (size_t)N_TOK * DIM;
  u16* Wkb = Wqb + (size_t)DIM * DIM;
  u16* Wvb = Wkb + (size_t)KVD * DIM;
  u16* Wob = Wvb + (size_t)KVD * DIM;
  u16* Qp  = Wob + (size_t)DIM * DIM;       // frag-packed Q (8MB)
  u16* Kp  = Qp  + (size_t)N_TOK * DIM;     // frag-packed K (1MB)
  u16* Vp  = Kp  + (size_t)N_TOK * KVD;     // frag-packed V (1MB)
  u16* Yb  = Vp  + (size_t)N_TOK * KVD;

  // fp32 -> bf16 (x + 4 weights); cos/sin consumed as fp32 by gemm_qkv
  cvt_all<<<dim3(13312), 256, 0, stream>>>(x, Wq, Wk, Wv, Wo, ws);

  // Fused QKV projection + RoPE, frag-packed outputs
  gemm_qkv<<<dim3(640), 256, 0, stream>>>(xb, Wqb, Wkb, Wvb, cs, sn, Qp, Kp, Vp);

  // Single-wave pipelined attention on frag-packed tensors
  attn_mfma<<<dim3(64, 32), 64, 0, stream>>>(Qp, Kp, Vp, Yb);

  // Output projection (fp32 straight to d_out)
  gemm_out<<<dim3(512), 256, 0, stream>>>(Yb, Wob, (float*)d_out);
}